// Round 5
// baseline (219.801 us; speedup 1.0000x reference)
//
#include <hip/hip_runtime.h>
#include <hip/hip_bf16.h>

// MoE MLP top-1 + shared expert. T=2048 H=768 I=2048 E=8, f32 in/out.
// R5: wconv rewritten as coalesced LDS-transpose streamer; stageB split into
//     shared (plain store) + routed (plain RMW) passes, no atomics, no out-memset.
//   wconv: f32 weights -> bf16 tiled (gate/up/down + shared as expert 8)
//   gather: x -> bf16 tiled Xc (scaled routed rows compact + raw shared rows)
//   stageA: P = silu(Xc Wg) * (Xc Wu)   (gll-only staging, 32 MFMA/wave/step)
//   stageB_sh: out = P_sh Wd_sh ; stageB_rt: out += P_rt Wd_e (unique owner)
// Chunk = 128 rows x 32 k bf16 (4096 u16 = 8KB), in-chunk addr:
//   ((row>>4)&7)*512 + ((k>>3)&3)*128 + (row&15)*8 + (k&7)
// gll16 copies a chunk linearly; MFMA fragment reads are linear-in-lane.

#define TT 2048
#define HH 768
#define II 2048
#define NE 8
#define RSLOTS 3072   // routed padded slots (24 tiles of 128)
#define LDSW 138      // wconv LDS row stride (u16): phase-2 banks conflict-free

typedef unsigned short u16;
typedef unsigned int u32;
typedef short s16x8 __attribute__((ext_vector_type(8)));
typedef u16 u16x8 __attribute__((ext_vector_type(8)));
typedef float f32x4 __attribute__((ext_vector_type(4)));

__device__ __forceinline__ u16 f2bf(float f) {  // f32 -> bf16 RNE
  u32 u = __builtin_bit_cast(u32, f);
  return (u16)((u + 0x7FFFu + ((u >> 16) & 1u)) >> 16);
}

typedef __attribute__((address_space(3))) u32 lds_u32;
typedef const __attribute__((address_space(1))) u32 glb_u32;
__device__ __forceinline__ void gll16(const void* g, void* l) {
  // global src per-lane; LDS dest wave-uniform base + lane*16 (linear)
  __builtin_amdgcn_global_load_lds((glb_u32*)g,
                                   (lds_u32*)(u32)(unsigned long long)l, 16, 0, 0);
}

// ---------------- router ----------------
__global__ void router_kernel(const float* __restrict__ x, const float* __restrict__ rw,
                              float* __restrict__ score, int* __restrict__ list,
                              int* __restrict__ cnt, float* __restrict__ probsum) {
  const int t = (int)((blockIdx.x * blockDim.x + threadIdx.x) >> 6);  // wave/token
  const int lane = threadIdx.x & 63;
  if (t >= TT) return;
  double acc[NE];
#pragma unroll
  for (int e = 0; e < NE; ++e) acc[e] = 0.0;
  const float* xr = x + (size_t)t * HH;
  for (int h = lane; h < HH; h += 64) {
    const double xv = (double)xr[h];
#pragma unroll
    for (int e = 0; e < NE; ++e) acc[e] += xv * (double)rw[h * NE + e];
  }
#pragma unroll
  for (int off = 32; off > 0; off >>= 1) {
#pragma unroll
    for (int e = 0; e < NE; ++e) acc[e] += __shfl_xor(acc[e], off);
  }
  if (lane == 0) {
    int best = 0;
#pragma unroll
    for (int e = 1; e < NE; ++e)
      if (acc[e] > acc[best]) best = e;  // strict > == first-max (jnp.argmax)
    const float sc = 1.0f / (1.0f + __expf((float)(-acc[best])));
    score[t] = sc;
    const int pos = atomicAdd(&cnt[best], 1);
    list[best * TT + pos] = t;
    atomicAdd(&probsum[best], sc);
  }
}

// ---------------- plan: padded segments + tile->expert + loss ----------------
__global__ void plan_kernel(const int* __restrict__ cnt, const float* __restrict__ probsum,
                            int* __restrict__ meta, float* __restrict__ out) {
  if (threadIdx.x == 0) {
    int S = 0;
    for (int e = 0; e < NE; ++e) {
      meta[e] = S;
      const int pad = (cnt[e] + 127) & ~127;
      for (int t = S >> 7; t < (S + pad) >> 7; ++t) meta[16 + t] = e;
      S += pad;
    }
    meta[8] = S;
    for (int t = S >> 7; t < 24; ++t) meta[16 + t] = 0;
    float s = 0.0f;
    for (int e = 0; e < NE; ++e) s += (float)cnt[e] * probsum[e];
    out[(size_t)TT * HH] = s * (0.001f * (float)NE / ((float)TT * (float)TT));
  }
}

// ---------------- gather: x -> tiled bf16 Xc (+tokmap) ----------------
__global__ __launch_bounds__(256) void gather_kernel(
    const float* __restrict__ x, const float* __restrict__ score,
    const int* __restrict__ list, const int* __restrict__ cnt,
    const int* __restrict__ meta, u16* __restrict__ Xc, int* __restrict__ tokmap) {
  const int task = blockIdx.x * 4 + (threadIdx.x >> 6);
  const int lane = threadIdx.x & 63;
  const int pb = task / 24;  // 16-row block, 0..319
  const int c = task % 24;   // k chunk
  const int fq = lane >> 4, fr = lane & 15;
  const int p = pb * 16 + fr;
  int tok;
  float sc;
  if (p >= RSLOTS) {
    tok = p - RSLOTS;
    sc = 1.0f;
  } else {
    const int e = meta[16 + (p >> 7)];
    const int idx = p - meta[e];
    tok = (idx >= 0 && idx < cnt[e]) ? list[e * TT + idx] : -1;
    sc = (tok >= 0) ? score[tok] : 0.0f;
  }
  u16x8 w = {0, 0, 0, 0, 0, 0, 0, 0};
  if (tok >= 0) {
    const float* xp = x + (size_t)tok * HH + c * 32 + fq * 8;
    const f32x4 a = *reinterpret_cast<const f32x4*>(xp);
    const f32x4 b = *reinterpret_cast<const f32x4*>(xp + 4);
#pragma unroll
    for (int j = 0; j < 4; ++j) {
      w[j] = f2bf(a[j] * sc);
      w[j + 4] = f2bf(b[j] * sc);
    }
  }
  *reinterpret_cast<u16x8*>(&Xc[((size_t)(pb >> 3) * 24 + c) * 4096 + (pb & 7) * 512 +
                                lane * 8]) = w;
  if (c == 0 && fq == 0) tokmap[p] = tok;
}

// ---------------- wconv: f32 weights -> bf16 tiled (LDS transpose) ----------------
// one block per chunk. ids: [0,6912) gate/up (9 x {g,u} x 16 nt x 24 kc);
//                 [6912,10368) down (9 x 6 nt x 64 kc). expert 8 = shared.
__global__ __launch_bounds__(256) void wconv_kernel(
    const float* __restrict__ gate_w, const float* __restrict__ up_w,
    const float* __restrict__ down_w, const float* __restrict__ sh_gate,
    const float* __restrict__ sh_up, const float* __restrict__ sh_down,
    u16* __restrict__ Wgt, u16* __restrict__ Wut, u16* __restrict__ Wdt) {
  const int id = blockIdx.x;
  const int t = threadIdx.x;
  const float* src;
  u16* dst;
  int N, n0, k0;
  if (id < 6912) {
    const int m = id / 384;  // 0..17: expert e=m>>1, mat=m&1
    const int r = id % 384;
    const int e = m >> 1;
    const int nt = r / 24, kc = r % 24;
    src = (m & 1) ? (e < 8 ? up_w + (size_t)e * HH * II : sh_up)
                  : (e < 8 ? gate_w + (size_t)e * HH * II : sh_gate);
    N = II; n0 = nt * 128; k0 = kc * 32;
    dst = ((m & 1) ? Wut : Wgt) + ((size_t)(e * 16 + nt) * 24 + kc) * 4096;
  } else {
    const int id2 = id - 6912;
    const int e = id2 / 384;
    const int r = id2 % 384;
    const int nt = r / 64, kc = r % 64;
    src = (e < 8) ? down_w + (size_t)e * II * HH : sh_down;
    N = HH; n0 = nt * 128; k0 = kc * 32;
    dst = Wdt + ((size_t)(e * 6 + nt) * 64 + kc) * 4096;
  }
  __shared__ u16 lds[32 * LDSW];
  // phase 1: coalesced f32x4 reads along n; bf16 rows into LDS
  {
    const int k = t >> 3;           // 0..31
    const int nb = (t & 7) * 16;    // 16 consecutive n per thread
    const float* rp = src + (size_t)(k0 + k) * N + n0 + nb;
    const f32x4 a0 = *reinterpret_cast<const f32x4*>(rp);
    const f32x4 a1 = *reinterpret_cast<const f32x4*>(rp + 4);
    const f32x4 a2 = *reinterpret_cast<const f32x4*>(rp + 8);
    const f32x4 a3 = *reinterpret_cast<const f32x4*>(rp + 12);
    u16x8 w0, w1;
#pragma unroll
    for (int j = 0; j < 4; ++j) {
      w0[j] = f2bf(a0[j]); w0[j + 4] = f2bf(a1[j]);
      w1[j] = f2bf(a2[j]); w1[j + 4] = f2bf(a3[j]);
    }
    *reinterpret_cast<u16x8*>(&lds[k * LDSW + nb]) = w0;
    *reinterpret_cast<u16x8*>(&lds[k * LDSW + nb + 8]) = w1;
  }
  __syncthreads();
  // phase 2: k-minor gather from LDS (conflict-free), coalesced u16x8 stores
#pragma unroll
  for (int r = 0; r < 2; ++r) {
    const int o = t + r * 256;          // 0..511
    const int fr = o & 15, fq = (o >> 4) & 3, nq = o >> 6;
    u16x8 w;
#pragma unroll
    for (int j = 0; j < 8; ++j) w[j] = lds[(fq * 8 + j) * LDSW + nq * 16 + fr];
    *reinterpret_cast<u16x8*>(&dst[o * 8]) = w;
  }
}

// ---------------- stage A: P = silu(Xc Wg) * (Xc Wu) ----------------
// grid (16 nt, 40 mty): mty<24 routed (early-exit past Rp), >=24 shared (e=8).
__global__ __launch_bounds__(256, 2) void stageA_kernel(
    const u16* __restrict__ Xc, const int* __restrict__ meta,
    const u16* __restrict__ Wgt, const u16* __restrict__ Wut, u16* __restrict__ P) {
  const int mty = blockIdx.y, nt = blockIdx.x;
  int e;
  if (mty < 24) {
    if (mty * 128 >= meta[8]) return;
    e = meta[16 + mty];
  } else {
    e = 8;
  }
  const u16* wg = Wgt + (size_t)(e * 16 + nt) * 24 * 4096;
  const u16* wu = Wut + (size_t)(e * 16 + nt) * 24 * 4096;
  const u16* xa = Xc + (size_t)mty * 24 * 4096;

  __shared__ u16 As[2][4096], Bgs[2][4096], Bus[2][4096];

  const int tid = threadIdx.x, lane = tid & 63, wid = tid >> 6;
  const int fr = lane & 15, fq = lane >> 4;
  const int wm4 = (wid >> 1) * 4;  // row 16-block base
  const int wn4 = (wid & 1) * 4;   // col 16-block base
  const int wn = (wid & 1) * 64;
  const int ncol = nt * 128;
  const int so = wid * 1024 + lane * 8;  // gll global src offset (u16)
  const int sl = wid * 1024;             // gll LDS dst offset (u16), wave-uniform

  f32x4 accg[4][4], accu[4][4];
#pragma unroll
  for (int i = 0; i < 4; ++i)
#pragma unroll
    for (int j = 0; j < 4; ++j) {
      accg[i][j] = f32x4{0.f, 0.f, 0.f, 0.f};
      accu[i][j] = f32x4{0.f, 0.f, 0.f, 0.f};
    }

  // full chunk = 4096 u16; 4 waves x 2 gll16 x 512 u16 each
#define STAGE(c, buf)                                               \
  {                                                                 \
    gll16(xa + (size_t)(c) * 4096 + so, &As[buf][sl]);              \
    gll16(xa + (size_t)(c) * 4096 + so + 512, &As[buf][sl + 512]);  \
    gll16(wg + (size_t)(c) * 4096 + so, &Bgs[buf][sl]);             \
    gll16(wg + (size_t)(c) * 4096 + so + 512, &Bgs[buf][sl + 512]); \
    gll16(wu + (size_t)(c) * 4096 + so, &Bus[buf][sl]);             \
    gll16(wu + (size_t)(c) * 4096 + so + 512, &Bus[buf][sl + 512]); \
  }

  STAGE(0, 0)
  __syncthreads();
  int cur = 0;
  for (int c = 0; c < 24; ++c) {
    if (c < 23) STAGE(c + 1, cur ^ 1)
    s16x8 af[4], bg[4], bu[4];
#pragma unroll
    for (int i = 0; i < 4; ++i) {
      af[i] = *reinterpret_cast<const s16x8*>(&As[cur][(wm4 + i) * 512 + fq * 128 + fr * 8]);
      bg[i] = *reinterpret_cast<const s16x8*>(&Bgs[cur][(wn4 + i) * 512 + fq * 128 + fr * 8]);
      bu[i] = *reinterpret_cast<const s16x8*>(&Bus[cur][(wn4 + i) * 512 + fq * 128 + fr * 8]);
    }
#pragma unroll
    for (int j = 0; j < 4; ++j)
#pragma unroll
      for (int i = 0; i < 4; ++i) {
        accg[i][j] = __builtin_amdgcn_mfma_f32_16x16x32_bf16(af[i], bg[j], accg[i][j], 0, 0, 0);
        accu[i][j] = __builtin_amdgcn_mfma_f32_16x16x32_bf16(af[i], bu[j], accu[i][j], 0, 0, 0);
      }
    __syncthreads();
    cur ^= 1;
  }
#undef STAGE

  // epilogue: silu(g)*u -> P tiled bf16 (C/D: row=fq*4+reg, col=fr)
#pragma unroll
  for (int i = 0; i < 4; ++i)
#pragma unroll
    for (int cc = 0; cc < 4; ++cc) {
      const int rlo = fq * 4 + cc;  // row & 15 within 16-block (wm4+i)
#pragma unroll
      for (int j = 0; j < 4; ++j) {
        const int k = ncol + wn + j * 16 + fr;  // global i-col
        const float gv = accg[i][j][cc];
        const float val = (gv / (1.0f + __expf(-gv))) * accu[i][j][cc];
        P[((size_t)mty * 64 + (k >> 5)) * 4096 + (size_t)(wm4 + i) * 512 +
          ((k >> 3) & 3) * 128 + rlo * 8 + (k & 7)] = f2bf(val);
      }
    }
}

// ---------------- stage B: out = / += P Wd ----------------
// SHARED=true: mty = 24 + by, plain stores (covers every out element).
// SHARED=false: mty = by (routed), plain non-atomic += (unique (tok,h) owner),
//               runs after the shared kernel on the stream.
template <bool SHARED>
__global__ __launch_bounds__(256, 2) void stageB_kernel(
    const u16* __restrict__ P, const int* __restrict__ meta,
    const int* __restrict__ tokmap, const u16* __restrict__ Wdt,
    float* __restrict__ out) {
  const int mty = SHARED ? 24 + blockIdx.y : blockIdx.y;
  const int nt = blockIdx.x;
  int e;
  if (SHARED) {
    e = 8;
  } else {
    if (mty * 128 >= meta[8]) return;
    e = meta[16 + mty];
  }
  const u16* wd = Wdt + (size_t)(e * 6 + nt) * 64 * 4096;
  const u16* pa = P + (size_t)mty * 64 * 4096;

  __shared__ u16 As[2][4096], Bs[2][4096];

  const int tid = threadIdx.x, lane = tid & 63, wid = tid >> 6;
  const int fr = lane & 15, fq = lane >> 4;
  const int wm4 = (wid >> 1) * 4;
  const int wn4 = (wid & 1) * 4;
  const int wm = (wid >> 1) * 64;
  const int wn = (wid & 1) * 64;
  const int ncol = nt * 128;
  const int so = wid * 1024 + lane * 8;
  const int sl = wid * 1024;

  f32x4 acc[4][4];
#pragma unroll
  for (int i = 0; i < 4; ++i)
#pragma unroll
    for (int j = 0; j < 4; ++j) acc[i][j] = f32x4{0.f, 0.f, 0.f, 0.f};

#define STAGEB(c, buf)                                              \
  {                                                                 \
    gll16(pa + (size_t)(c) * 4096 + so, &As[buf][sl]);              \
    gll16(pa + (size_t)(c) * 4096 + so + 512, &As[buf][sl + 512]);  \
    gll16(wd + (size_t)(c) * 4096 + so, &Bs[buf][sl]);              \
    gll16(wd + (size_t)(c) * 4096 + so + 512, &Bs[buf][sl + 512]);  \
  }

  STAGEB(0, 0)
  __syncthreads();
  int cur = 0;
  for (int c = 0; c < 64; ++c) {
    if (c < 63) STAGEB(c + 1, cur ^ 1)
    s16x8 af[4], bf[4];
#pragma unroll
    for (int i = 0; i < 4; ++i) {
      af[i] = *reinterpret_cast<const s16x8*>(&As[cur][(wm4 + i) * 512 + fq * 128 + fr * 8]);
      bf[i] = *reinterpret_cast<const s16x8*>(&Bs[cur][(wn4 + i) * 512 + fq * 128 + fr * 8]);
    }
#pragma unroll
    for (int j = 0; j < 4; ++j)
#pragma unroll
      for (int i = 0; i < 4; ++i)
        acc[i][j] = __builtin_amdgcn_mfma_f32_16x16x32_bf16(af[i], bf[j], acc[i][j], 0, 0, 0);
    __syncthreads();
    cur ^= 1;
  }
#undef STAGEB

#pragma unroll
  for (int i = 0; i < 4; ++i)
#pragma unroll
    for (int cc = 0; cc < 4; ++cc) {
      const int p = mty * 128 + wm + i * 16 + fq * 4 + cc;
      const int tok = tokmap[p];
      if (SHARED) {
#pragma unroll
        for (int j = 0; j < 4; ++j)
          out[(size_t)tok * HH + ncol + wn + j * 16 + fr] = acc[i][j][cc];
      } else if (tok >= 0) {
#pragma unroll
        for (int j = 0; j < 4; ++j)
          out[(size_t)tok * HH + ncol + wn + j * 16 + fr] += acc[i][j][cc];
      }
    }
}

// ---------------- launcher ----------------
extern "C" void kernel_launch(void* const* d_in, const int* in_sizes, int n_in,
                              void* d_out, int out_size, void* d_ws, size_t ws_size,
                              hipStream_t stream) {
  (void)in_sizes; (void)n_in; (void)out_size; (void)ws_size;
  const float* x = (const float*)d_in[0];
  const float* rw = (const float*)d_in[1];
  const float* gate_w = (const float*)d_in[2];
  const float* up_w = (const float*)d_in[3];
  const float* down_w = (const float*)d_in[4];
  const float* sh_gate = (const float*)d_in[5];
  const float* sh_up = (const float*)d_in[6];
  const float* sh_down = (const float*)d_in[7];
  float* out = (float*)d_out;

  char* ws = (char*)d_ws;
  size_t off = 0;
  u16* Xc = (u16*)(ws + off);  off += (size_t)(RSLOTS + TT) * HH * sizeof(u16);   // 7.9MB
  u16* P = (u16*)(ws + off);   off += (size_t)(RSLOTS + TT) * II * sizeof(u16);   // 21MB
  u16* Wgt = (u16*)(ws + off); off += (size_t)9 * 16 * 24 * 4096 * sizeof(u16);   // 28.3MB
  u16* Wut = (u16*)(ws + off); off += (size_t)9 * 16 * 24 * 4096 * sizeof(u16);   // 28.3MB
  u16* Wdt = (u16*)(ws + off); off += (size_t)9 * 6 * 64 * 4096 * sizeof(u16);    // 28.3MB
  float* score = (float*)(ws + off);   off += TT * sizeof(float);
  int* list = (int*)(ws + off);        off += (size_t)NE * TT * sizeof(int);
  int* cnt = (int*)(ws + off);         off += 16 * sizeof(int);
  float* probsum = (float*)(ws + off); off += 16 * sizeof(float);
  int* meta = (int*)(ws + off);        off += 64 * sizeof(int);
  int* tokmap = (int*)(ws + off);

  hipMemsetAsync(cnt, 0, 16 * sizeof(int) + 16 * sizeof(float), stream);
  wconv_kernel<<<dim3(10368), dim3(256), 0, stream>>>(gate_w, up_w, down_w, sh_gate,
                                                      sh_up, sh_down, Wgt, Wut, Wdt);
  router_kernel<<<dim3(512), dim3(256), 0, stream>>>(x, rw, score, list, cnt, probsum);
  plan_kernel<<<dim3(1), dim3(64), 0, stream>>>(cnt, probsum, meta, out);
  gather_kernel<<<dim3(1920), dim3(256), 0, stream>>>(x, score, list, cnt, meta, Xc,
                                                      tokmap);
  stageA_kernel<<<dim3(16, 40, 1), dim3(256), 0, stream>>>(Xc, meta, Wgt, Wut, P);
  stageB_kernel<true><<<dim3(6, 16, 1), dim3(256), 0, stream>>>(P, meta, tokmap, Wdt, out);
  stageB_kernel<false><<<dim3(6, 24, 1), dim3(256), 0, stream>>>(P, meta, tokmap, Wdt, out);
}

// Round 6
// 200.801 us; speedup vs baseline: 1.0946x; 1.0946x over previous
//
#include <hip/hip_runtime.h>
#include <hip/hip_bf16.h>

// MoE MLP top-1 + shared expert. T=2048 H=768 I=2048 E=8, f32 in/out.
// R6: wconv = grid-stride 8-chunk double-buffered pipeline (1296 blocks);
//     stageB reverted to single atomic kernel (R4) + out memset.
//   wconv: f32 weights -> bf16 tiled (gate/up/down + shared as expert 8)
//   gather: x -> bf16 tiled Xc (scaled routed rows compact + raw shared rows)
//   stageA: P = silu(Xc Wg) * (Xc Wu)   (gll-only staging, 32 MFMA/wave/step)
//   stageB: out += P Wd (atomicAdd epilogue via tokmap, out pre-zeroed)
// Chunk = 128 rows x 32 k bf16 (4096 u16 = 8KB), in-chunk addr:
//   ((row>>4)&7)*512 + ((k>>3)&3)*128 + (row&15)*8 + (k&7)
// gll16 copies a chunk linearly; MFMA fragment reads are linear-in-lane.

#define TT 2048
#define HH 768
#define II 2048
#define NE 8
#define RSLOTS 3072   // routed padded slots (24 tiles of 128)
#define LDSW 138      // wconv LDS row stride (u16)
#define WGRID 1296    // wconv blocks; x8 chunks = 10368 total

typedef unsigned short u16;
typedef unsigned int u32;
typedef short s16x8 __attribute__((ext_vector_type(8)));
typedef u16 u16x8 __attribute__((ext_vector_type(8)));
typedef float f32x4 __attribute__((ext_vector_type(4)));

__device__ __forceinline__ u16 f2bf(float f) {  // f32 -> bf16 RNE
  u32 u = __builtin_bit_cast(u32, f);
  return (u16)((u + 0x7FFFu + ((u >> 16) & 1u)) >> 16);
}

typedef __attribute__((address_space(3))) u32 lds_u32;
typedef const __attribute__((address_space(1))) u32 glb_u32;
__device__ __forceinline__ void gll16(const void* g, void* l) {
  // global src per-lane; LDS dest wave-uniform base + lane*16 (linear)
  __builtin_amdgcn_global_load_lds((glb_u32*)g,
                                   (lds_u32*)(u32)(unsigned long long)l, 16, 0, 0);
}

// ---------------- router ----------------
__global__ void router_kernel(const float* __restrict__ x, const float* __restrict__ rw,
                              float* __restrict__ score, int* __restrict__ list,
                              int* __restrict__ cnt, float* __restrict__ probsum) {
  const int t = (int)((blockIdx.x * blockDim.x + threadIdx.x) >> 6);  // wave/token
  const int lane = threadIdx.x & 63;
  if (t >= TT) return;
  double acc[NE];
#pragma unroll
  for (int e = 0; e < NE; ++e) acc[e] = 0.0;
  const float* xr = x + (size_t)t * HH;
  for (int h = lane; h < HH; h += 64) {
    const double xv = (double)xr[h];
#pragma unroll
    for (int e = 0; e < NE; ++e) acc[e] += xv * (double)rw[h * NE + e];
  }
#pragma unroll
  for (int off = 32; off > 0; off >>= 1) {
#pragma unroll
    for (int e = 0; e < NE; ++e) acc[e] += __shfl_xor(acc[e], off);
  }
  if (lane == 0) {
    int best = 0;
#pragma unroll
    for (int e = 1; e < NE; ++e)
      if (acc[e] > acc[best]) best = e;  // strict > == first-max (jnp.argmax)
    const float sc = 1.0f / (1.0f + __expf((float)(-acc[best])));
    score[t] = sc;
    const int pos = atomicAdd(&cnt[best], 1);
    list[best * TT + pos] = t;
    atomicAdd(&probsum[best], sc);
  }
}

// ---------------- plan: padded segments + tile->expert + loss ----------------
__global__ void plan_kernel(const int* __restrict__ cnt, const float* __restrict__ probsum,
                            int* __restrict__ meta, float* __restrict__ out) {
  if (threadIdx.x == 0) {
    int S = 0;
    for (int e = 0; e < NE; ++e) {
      meta[e] = S;
      const int pad = (cnt[e] + 127) & ~127;
      for (int t = S >> 7; t < (S + pad) >> 7; ++t) meta[16 + t] = e;
      S += pad;
    }
    meta[8] = S;
    for (int t = S >> 7; t < 24; ++t) meta[16 + t] = 0;
    float s = 0.0f;
    for (int e = 0; e < NE; ++e) s += (float)cnt[e] * probsum[e];
    out[(size_t)TT * HH] = s * (0.001f * (float)NE / ((float)TT * (float)TT));
  }
}

// ---------------- gather: x -> tiled bf16 Xc (+tokmap) ----------------
__global__ __launch_bounds__(256) void gather_kernel(
    const float* __restrict__ x, const float* __restrict__ score,
    const int* __restrict__ list, const int* __restrict__ cnt,
    const int* __restrict__ meta, u16* __restrict__ Xc, int* __restrict__ tokmap) {
  const int task = blockIdx.x * 4 + (threadIdx.x >> 6);
  const int lane = threadIdx.x & 63;
  const int pb = task / 24;  // 16-row block, 0..319
  const int c = task % 24;   // k chunk
  const int fq = lane >> 4, fr = lane & 15;
  const int p = pb * 16 + fr;
  int tok;
  float sc;
  if (p >= RSLOTS) {
    tok = p - RSLOTS;
    sc = 1.0f;
  } else {
    const int e = meta[16 + (p >> 7)];
    const int idx = p - meta[e];
    tok = (idx >= 0 && idx < cnt[e]) ? list[e * TT + idx] : -1;
    sc = (tok >= 0) ? score[tok] : 0.0f;
  }
  u16x8 w = {0, 0, 0, 0, 0, 0, 0, 0};
  if (tok >= 0) {
    const float* xp = x + (size_t)tok * HH + c * 32 + fq * 8;
    const f32x4 a = *reinterpret_cast<const f32x4*>(xp);
    const f32x4 b = *reinterpret_cast<const f32x4*>(xp + 4);
#pragma unroll
    for (int j = 0; j < 4; ++j) {
      w[j] = f2bf(a[j] * sc);
      w[j + 4] = f2bf(b[j] * sc);
    }
  }
  *reinterpret_cast<u16x8*>(&Xc[((size_t)(pb >> 3) * 24 + c) * 4096 + (pb & 7) * 512 +
                                lane * 8]) = w;
  if (c == 0 && fq == 0) tokmap[p] = tok;
}

// ---------------- wconv: f32 weights -> bf16 tiled ----------------
// chunk ids: [0,6912) gate/up (9 x {g,u} x 16 nt x 24 kc);
//            [6912,10368) down (9 x 6 nt x 64 kc). expert 8 = shared.
__device__ __forceinline__ void wc_map(
    int id, const float* gw, const float* uw, const float* dw, const float* sg,
    const float* su, const float* sd, u16* Wgt, u16* Wut, u16* Wdt,
    const float*& src, u16*& dst, int& N) {
  if (id < 6912) {
    const int m = id / 384, r = id % 384;
    const int e = m >> 1;
    const int nt = r / 24, kc = r % 24;
    const float* base = (m & 1) ? (e < 8 ? uw + (size_t)e * HH * II : su)
                                : (e < 8 ? gw + (size_t)e * HH * II : sg);
    N = II;
    src = base + (size_t)(kc * 32) * II + nt * 128;
    dst = ((m & 1) ? Wut : Wgt) + ((size_t)(e * 16 + nt) * 24 + kc) * 4096;
  } else {
    const int id2 = id - 6912;
    const int e = id2 / 384, r = id2 % 384;
    const int nt = r / 64, kc = r % 64;
    N = HH;
    src = ((e < 8) ? dw + (size_t)e * II * HH : sd) + (size_t)(kc * 32) * HH + nt * 128;
    dst = Wdt + ((size_t)(e * 6 + nt) * 64 + kc) * 4096;
  }
}

__global__ __launch_bounds__(256) void wconv_kernel(
    const float* __restrict__ gate_w, const float* __restrict__ up_w,
    const float* __restrict__ down_w, const float* __restrict__ sh_gate,
    const float* __restrict__ sh_up, const float* __restrict__ sh_down,
    u16* __restrict__ Wgt, u16* __restrict__ Wut, u16* __restrict__ Wdt) {
  const int t = threadIdx.x;
  const int k = t >> 3;           // 0..31 (k row)
  const int nb = (t & 7) * 16;    // 16 consecutive n per thread
  __shared__ u16 lds[2][32 * LDSW];

  const float* src;
  u16* dst;
  int N;
  wc_map(blockIdx.x, gate_w, up_w, down_w, sh_gate, sh_up, sh_down, Wgt, Wut, Wdt,
         src, dst, N);
  f32x4 a0, a1, a2, a3, b0, b1, b2, b3;
  {
    const float* rp = src + (size_t)k * N + nb;
    a0 = *reinterpret_cast<const f32x4*>(rp);
    a1 = *reinterpret_cast<const f32x4*>(rp + 4);
    a2 = *reinterpret_cast<const f32x4*>(rp + 8);
    a3 = *reinterpret_cast<const f32x4*>(rp + 12);
  }
#pragma unroll
  for (int kk = 0; kk < 8; ++kk) {
    const int buf = kk & 1;
    {  // phase 1: convert + LDS rows
      u16x8 w0, w1;
#pragma unroll
      for (int j = 0; j < 4; ++j) {
        w0[j] = f2bf(a0[j]); w0[j + 4] = f2bf(a1[j]);
        w1[j] = f2bf(a2[j]); w1[j + 4] = f2bf(a3[j]);
      }
      *reinterpret_cast<u16x8*>(&lds[buf][k * LDSW + nb]) = w0;
      *reinterpret_cast<u16x8*>(&lds[buf][k * LDSW + nb + 8]) = w1;
    }
    const float* nsrc = src;
    u16* ndst = dst;
    if (kk < 7) {  // issue next chunk's loads; latency hides under phase 2
      int nN;
      wc_map(blockIdx.x + (kk + 1) * WGRID, gate_w, up_w, down_w, sh_gate, sh_up,
             sh_down, Wgt, Wut, Wdt, nsrc, ndst, nN);
      const float* rp = nsrc + (size_t)k * nN + nb;
      b0 = *reinterpret_cast<const f32x4*>(rp);
      b1 = *reinterpret_cast<const f32x4*>(rp + 4);
      b2 = *reinterpret_cast<const f32x4*>(rp + 8);
      b3 = *reinterpret_cast<const f32x4*>(rp + 12);
    }
    __syncthreads();
    // phase 2: k-minor gather from LDS (conflict-free), coalesced u16x8 stores
#pragma unroll
    for (int r = 0; r < 2; ++r) {
      const int o = t + r * 256;  // 0..511
      const int fr = o & 15, fq = (o >> 4) & 3, nq = o >> 6;
      u16x8 w;
#pragma unroll
      for (int j = 0; j < 8; ++j) w[j] = lds[buf][(fq * 8 + j) * LDSW + nq * 16 + fr];
      *reinterpret_cast<u16x8*>(&dst[o * 8]) = w;
    }
    a0 = b0; a1 = b1; a2 = b2; a3 = b3;
    src = nsrc; dst = ndst;
  }
}

// ---------------- stage A: P = silu(Xc Wg) * (Xc Wu) ----------------
// grid (16 nt, 40 mty): mty<24 routed (early-exit past Rp), >=24 shared (e=8).
__global__ __launch_bounds__(256, 2) void stageA_kernel(
    const u16* __restrict__ Xc, const int* __restrict__ meta,
    const u16* __restrict__ Wgt, const u16* __restrict__ Wut, u16* __restrict__ P) {
  const int mty = blockIdx.y, nt = blockIdx.x;
  int e;
  if (mty < 24) {
    if (mty * 128 >= meta[8]) return;
    e = meta[16 + mty];
  } else {
    e = 8;
  }
  const u16* wg = Wgt + (size_t)(e * 16 + nt) * 24 * 4096;
  const u16* wu = Wut + (size_t)(e * 16 + nt) * 24 * 4096;
  const u16* xa = Xc + (size_t)mty * 24 * 4096;

  __shared__ u16 As[2][4096], Bgs[2][4096], Bus[2][4096];

  const int tid = threadIdx.x, lane = tid & 63, wid = tid >> 6;
  const int fr = lane & 15, fq = lane >> 4;
  const int wm4 = (wid >> 1) * 4;  // row 16-block base
  const int wn4 = (wid & 1) * 4;   // col 16-block base
  const int wn = (wid & 1) * 64;
  const int ncol = nt * 128;
  const int so = wid * 1024 + lane * 8;  // gll global src offset (u16)
  const int sl = wid * 1024;             // gll LDS dst offset (u16), wave-uniform

  f32x4 accg[4][4], accu[4][4];
#pragma unroll
  for (int i = 0; i < 4; ++i)
#pragma unroll
    for (int j = 0; j < 4; ++j) {
      accg[i][j] = f32x4{0.f, 0.f, 0.f, 0.f};
      accu[i][j] = f32x4{0.f, 0.f, 0.f, 0.f};
    }

  // full chunk = 4096 u16; 4 waves x 2 gll16 x 512 u16 each
#define STAGE(c, buf)                                               \
  {                                                                 \
    gll16(xa + (size_t)(c) * 4096 + so, &As[buf][sl]);              \
    gll16(xa + (size_t)(c) * 4096 + so + 512, &As[buf][sl + 512]);  \
    gll16(wg + (size_t)(c) * 4096 + so, &Bgs[buf][sl]);             \
    gll16(wg + (size_t)(c) * 4096 + so + 512, &Bgs[buf][sl + 512]); \
    gll16(wu + (size_t)(c) * 4096 + so, &Bus[buf][sl]);             \
    gll16(wu + (size_t)(c) * 4096 + so + 512, &Bus[buf][sl + 512]); \
  }

  STAGE(0, 0)
  __syncthreads();
  int cur = 0;
  for (int c = 0; c < 24; ++c) {
    if (c < 23) STAGE(c + 1, cur ^ 1)
    s16x8 af[4], bg[4], bu[4];
#pragma unroll
    for (int i = 0; i < 4; ++i) {
      af[i] = *reinterpret_cast<const s16x8*>(&As[cur][(wm4 + i) * 512 + fq * 128 + fr * 8]);
      bg[i] = *reinterpret_cast<const s16x8*>(&Bgs[cur][(wn4 + i) * 512 + fq * 128 + fr * 8]);
      bu[i] = *reinterpret_cast<const s16x8*>(&Bus[cur][(wn4 + i) * 512 + fq * 128 + fr * 8]);
    }
#pragma unroll
    for (int j = 0; j < 4; ++j)
#pragma unroll
      for (int i = 0; i < 4; ++i) {
        accg[i][j] = __builtin_amdgcn_mfma_f32_16x16x32_bf16(af[i], bg[j], accg[i][j], 0, 0, 0);
        accu[i][j] = __builtin_amdgcn_mfma_f32_16x16x32_bf16(af[i], bu[j], accu[i][j], 0, 0, 0);
      }
    __syncthreads();
    cur ^= 1;
  }
#undef STAGE

  // epilogue: silu(g)*u -> P tiled bf16 (C/D: row=fq*4+reg, col=fr)
#pragma unroll
  for (int i = 0; i < 4; ++i)
#pragma unroll
    for (int cc = 0; cc < 4; ++cc) {
      const int rlo = fq * 4 + cc;  // row & 15 within 16-block (wm4+i)
#pragma unroll
      for (int j = 0; j < 4; ++j) {
        const int k = ncol + wn + j * 16 + fr;  // global i-col
        const float gv = accg[i][j][cc];
        const float val = (gv / (1.0f + __expf(-gv))) * accu[i][j][cc];
        P[((size_t)mty * 64 + (k >> 5)) * 4096 + (size_t)(wm4 + i) * 512 +
          ((k >> 3) & 3) * 128 + rlo * 8 + (k & 7)] = f2bf(val);
      }
    }
}

// ---------------- stage B: out += P Wd (atomicAdd, out pre-zeroed) ----------------
// grid (6 nt, 40 mty); each out element gets one shared + at most one routed add.
__global__ __launch_bounds__(256, 2) void stageB_kernel(
    const u16* __restrict__ P, const int* __restrict__ meta,
    const int* __restrict__ tokmap, const u16* __restrict__ Wdt,
    float* __restrict__ out) {
  const int mty = blockIdx.y, nt = blockIdx.x;
  int e;
  if (mty < 24) {
    if (mty * 128 >= meta[8]) return;
    e = meta[16 + mty];
  } else {
    e = 8;
  }
  const u16* wd = Wdt + (size_t)(e * 6 + nt) * 64 * 4096;
  const u16* pa = P + (size_t)mty * 64 * 4096;

  __shared__ u16 As[2][4096], Bs[2][4096];

  const int tid = threadIdx.x, lane = tid & 63, wid = tid >> 6;
  const int fr = lane & 15, fq = lane >> 4;
  const int wm4 = (wid >> 1) * 4;
  const int wn4 = (wid & 1) * 4;
  const int wm = (wid >> 1) * 64;
  const int wn = (wid & 1) * 64;
  const int ncol = nt * 128;
  const int so = wid * 1024 + lane * 8;
  const int sl = wid * 1024;

  f32x4 acc[4][4];
#pragma unroll
  for (int i = 0; i < 4; ++i)
#pragma unroll
    for (int j = 0; j < 4; ++j) acc[i][j] = f32x4{0.f, 0.f, 0.f, 0.f};

#define STAGEB(c, buf)                                              \
  {                                                                 \
    gll16(pa + (size_t)(c) * 4096 + so, &As[buf][sl]);              \
    gll16(pa + (size_t)(c) * 4096 + so + 512, &As[buf][sl + 512]);  \
    gll16(wd + (size_t)(c) * 4096 + so, &Bs[buf][sl]);              \
    gll16(wd + (size_t)(c) * 4096 + so + 512, &Bs[buf][sl + 512]);  \
  }

  STAGEB(0, 0)
  __syncthreads();
  int cur = 0;
  for (int c = 0; c < 64; ++c) {
    if (c < 63) STAGEB(c + 1, cur ^ 1)
    s16x8 af[4], bf[4];
#pragma unroll
    for (int i = 0; i < 4; ++i) {
      af[i] = *reinterpret_cast<const s16x8*>(&As[cur][(wm4 + i) * 512 + fq * 128 + fr * 8]);
      bf[i] = *reinterpret_cast<const s16x8*>(&Bs[cur][(wn4 + i) * 512 + fq * 128 + fr * 8]);
    }
#pragma unroll
    for (int j = 0; j < 4; ++j)
#pragma unroll
      for (int i = 0; i < 4; ++i)
        acc[i][j] = __builtin_amdgcn_mfma_f32_16x16x32_bf16(af[i], bf[j], acc[i][j], 0, 0, 0);
    __syncthreads();
    cur ^= 1;
  }
#undef STAGEB

#pragma unroll
  for (int i = 0; i < 4; ++i)
#pragma unroll
    for (int cc = 0; cc < 4; ++cc) {
      const int p = mty * 128 + wm + i * 16 + fq * 4 + cc;
      const int tok = tokmap[p];
      if (tok >= 0) {
#pragma unroll
        for (int j = 0; j < 4; ++j)
          atomicAdd(&out[(size_t)tok * HH + ncol + wn + j * 16 + fr], acc[i][j][cc]);
      }
    }
}

// ---------------- launcher ----------------
extern "C" void kernel_launch(void* const* d_in, const int* in_sizes, int n_in,
                              void* d_out, int out_size, void* d_ws, size_t ws_size,
                              hipStream_t stream) {
  (void)in_sizes; (void)n_in; (void)ws_size;
  const float* x = (const float*)d_in[0];
  const float* rw = (const float*)d_in[1];
  const float* gate_w = (const float*)d_in[2];
  const float* up_w = (const float*)d_in[3];
  const float* down_w = (const float*)d_in[4];
  const float* sh_gate = (const float*)d_in[5];
  const float* sh_up = (const float*)d_in[6];
  const float* sh_down = (const float*)d_in[7];
  float* out = (float*)d_out;

  char* ws = (char*)d_ws;
  size_t off = 0;
  u16* Xc = (u16*)(ws + off);  off += (size_t)(RSLOTS + TT) * HH * sizeof(u16);   // 7.9MB
  u16* P = (u16*)(ws + off);   off += (size_t)(RSLOTS + TT) * II * sizeof(u16);   // 21MB
  u16* Wgt = (u16*)(ws + off); off += (size_t)9 * 16 * 24 * 4096 * sizeof(u16);   // 28.3MB
  u16* Wut = (u16*)(ws + off); off += (size_t)9 * 16 * 24 * 4096 * sizeof(u16);   // 28.3MB
  u16* Wdt = (u16*)(ws + off); off += (size_t)9 * 6 * 64 * 4096 * sizeof(u16);    // 28.3MB
  float* score = (float*)(ws + off);   off += TT * sizeof(float);
  int* list = (int*)(ws + off);        off += (size_t)NE * TT * sizeof(int);
  int* cnt = (int*)(ws + off);         off += 16 * sizeof(int);
  float* probsum = (float*)(ws + off); off += 16 * sizeof(float);
  int* meta = (int*)(ws + off);        off += 64 * sizeof(int);
  int* tokmap = (int*)(ws + off);

  hipMemsetAsync(d_out, 0, (size_t)out_size * sizeof(float), stream);
  hipMemsetAsync(cnt, 0, 16 * sizeof(int) + 16 * sizeof(float), stream);
  wconv_kernel<<<dim3(WGRID), dim3(256), 0, stream>>>(gate_w, up_w, down_w, sh_gate,
                                                      sh_up, sh_down, Wgt, Wut, Wdt);
  router_kernel<<<dim3(512), dim3(256), 0, stream>>>(x, rw, score, list, cnt, probsum);
  plan_kernel<<<dim3(1), dim3(64), 0, stream>>>(cnt, probsum, meta, out);
  gather_kernel<<<dim3(1920), dim3(256), 0, stream>>>(x, score, list, cnt, meta, Xc,
                                                      tokmap);
  stageA_kernel<<<dim3(16, 40, 1), dim3(256), 0, stream>>>(Xc, meta, Wgt, Wut, P);
  stageB_kernel<<<dim3(6, 40, 1), dim3(256), 0, stream>>>(P, meta, tokmap, Wdt, out);
}

// Round 7
// 180.589 us; speedup vs baseline: 1.2171x; 1.1119x over previous
//
#include <hip/hip_runtime.h>
#include <hip/hip_bf16.h>

// MoE MLP top-1 + shared expert. T=2048 H=768 I=2048 E=8, f32 in/out.
// R7: wconv = gll16-staged f32 chunks (async, un-sinkable) + LDS transpose,
//     2-phase double-buffer, 1 barrier/chunk; router fused into wconv grid.
//   wconv: f32 weights -> bf16 tiled (gate/up/down + shared as expert 8)
//   gather: x -> bf16 tiled Xc (scaled routed rows compact + raw shared rows)
//   stageA: P = silu(Xc Wg) * (Xc Wu)   (gll-only staging, 32 MFMA/wave/step)
//   stageB: out += P Wd (atomicAdd epilogue via tokmap, out pre-zeroed)
// Chunk = 128 rows x 32 k bf16 (4096 u16 = 8KB), in-chunk addr:
//   ((row>>4)&7)*512 + ((k>>3)&3)*128 + (row&15)*8 + (k&7)
// gll16 copies chunks linearly; MFMA fragment reads are linear-in-lane.

#define TT 2048
#define HH 768
#define II 2048
#define NE 8
#define RSLOTS 3072   // routed padded slots (24 tiles of 128)
#define WGRID 1296    // wconv blocks; x8 chunks = 10368 total

typedef unsigned short u16;
typedef unsigned int u32;
typedef short s16x8 __attribute__((ext_vector_type(8)));
typedef u16 u16x8 __attribute__((ext_vector_type(8)));
typedef float f32x4 __attribute__((ext_vector_type(4)));

__device__ __forceinline__ u16 f2bf(float f) {  // f32 -> bf16 RNE
  u32 u = __builtin_bit_cast(u32, f);
  return (u16)((u + 0x7FFFu + ((u >> 16) & 1u)) >> 16);
}

typedef __attribute__((address_space(3))) u32 lds_u32;
typedef const __attribute__((address_space(1))) u32 glb_u32;
__device__ __forceinline__ void gll16(const void* g, void* l) {
  // global src per-lane; LDS dest wave-uniform base + lane*16 (linear)
  __builtin_amdgcn_global_load_lds((glb_u32*)g,
                                   (lds_u32*)(u32)(unsigned long long)l, 16, 0, 0);
}

// ---------------- wconv chunk map ----------------
// chunk ids: [0,6912) gate/up (9 x {g,u} x 16 nt x 24 kc);
//            [6912,10368) down (9 x 6 nt x 64 kc). expert 8 = shared.
__device__ __forceinline__ void wc_map(
    int id, const float* gw, const float* uw, const float* dw, const float* sg,
    const float* su, const float* sd, u16* Wgt, u16* Wut, u16* Wdt,
    const float*& src, u16*& dst, int& N) {
  if (id < 6912) {
    const int m = id / 384, r = id % 384;
    const int e = m >> 1;
    const int nt = r / 24, kc = r % 24;
    const float* base = (m & 1) ? (e < 8 ? uw + (size_t)e * HH * II : su)
                                : (e < 8 ? gw + (size_t)e * HH * II : sg);
    N = II;
    src = base + (size_t)(kc * 32) * II + nt * 128;
    dst = ((m & 1) ? Wut : Wgt) + ((size_t)(e * 16 + nt) * 24 + kc) * 4096;
  } else {
    const int id2 = id - 6912;
    const int e = id2 / 384, r = id2 % 384;
    const int nt = r / 64, kc = r % 64;
    N = HH;
    src = ((e < 8) ? dw + (size_t)e * II * HH : sd) + (size_t)(kc * 32) * HH + nt * 128;
    dst = Wdt + ((size_t)(e * 6 + nt) * 64 + kc) * 4096;
  }
}

// wave wid stages rows [wid*8, wid*8+8) of a [32][N-strided] f32 chunk into
// linear LDS [32][128] f32 (4 gll16 issues of 2 rows each).
__device__ __forceinline__ void wc_issue(const float* src, int N, float* ldsbuf,
                                         int wid, int lane) {
  const int rrow = lane >> 5;          // row within pair
  const int col4 = (lane & 31) * 4;    // 4 f32 per lane
#pragma unroll
  for (int q = 0; q < 4; ++q) {
    const int row = wid * 8 + q * 2;
    gll16(src + (size_t)(row + rrow) * N + col4, ldsbuf + (size_t)row * 128);
  }
}

// ---------------- fused wconv + router ----------------
__global__ __launch_bounds__(256) void wconv_router_kernel(
    const float* __restrict__ gate_w, const float* __restrict__ up_w,
    const float* __restrict__ down_w, const float* __restrict__ sh_gate,
    const float* __restrict__ sh_up, const float* __restrict__ sh_down,
    u16* __restrict__ Wgt, u16* __restrict__ Wut, u16* __restrict__ Wdt,
    const float* __restrict__ x, const float* __restrict__ rw,
    float* __restrict__ score, int* __restrict__ list, int* __restrict__ cnt,
    float* __restrict__ probsum) {
  __shared__ float ldsf[2][32 * 128];
  if (blockIdx.x >= WGRID) {
    // ---- router: one wave per token ----
    const int t = (int)(((blockIdx.x - WGRID) * 256 + threadIdx.x) >> 6);
    const int lane = threadIdx.x & 63;
    if (t >= TT) return;
    double acc[NE];
#pragma unroll
    for (int e = 0; e < NE; ++e) acc[e] = 0.0;
    const float* xr = x + (size_t)t * HH;
    for (int h = lane; h < HH; h += 64) {
      const double xv = (double)xr[h];
#pragma unroll
      for (int e = 0; e < NE; ++e) acc[e] += xv * (double)rw[h * NE + e];
    }
#pragma unroll
    for (int off = 32; off > 0; off >>= 1) {
#pragma unroll
      for (int e = 0; e < NE; ++e) acc[e] += __shfl_xor(acc[e], off);
    }
    if (lane == 0) {
      int best = 0;
#pragma unroll
      for (int e = 1; e < NE; ++e)
        if (acc[e] > acc[best]) best = e;  // strict > == first-max (jnp.argmax)
      const float sc = 1.0f / (1.0f + __expf((float)(-acc[best])));
      score[t] = sc;
      const int pos = atomicAdd(&cnt[best], 1);
      list[best * TT + pos] = t;
      atomicAdd(&probsum[best], sc);
    }
    return;
  }
  // ---- wconv: 8 chunks, double-buffered, 1 barrier/chunk ----
  const int t = threadIdx.x;
  const int wid = t >> 6, lane = t & 63;
  const float* src;
  u16* dst;
  int N;
  wc_map(blockIdx.x, gate_w, up_w, down_w, sh_gate, sh_up, sh_down, Wgt, Wut, Wdt,
         src, dst, N);
  wc_issue(src, N, ldsf[0], wid, lane);
  __syncthreads();
#pragma unroll
  for (int kk = 0; kk < 8; ++kk) {
    const int buf = kk & 1;
    const float* nsrc = nullptr;
    u16* ndst = nullptr;
    int nN = 0;
    if (kk < 7) {  // issue next chunk into other buffer (async, in flight
                   // across phase 2; drained at the barrier below)
      wc_map(blockIdx.x + (kk + 1) * WGRID, gate_w, up_w, down_w, sh_gate, sh_up,
             sh_down, Wgt, Wut, Wdt, nsrc, ndst, nN);
      wc_issue(nsrc, nN, ldsf[buf ^ 1], wid, lane);
    }
    // phase 2: k-minor gather from f32 LDS, convert, coalesced u16x8 stores
#pragma unroll
    for (int r = 0; r < 2; ++r) {
      const int o = t + r * 256;  // 0..511
      const int fr = o & 15, fq = (o >> 4) & 3, nq = o >> 6;
      const float* lp = &ldsf[buf][(fq * 8) * 128 + nq * 16 + fr];
      u16x8 w;
#pragma unroll
      for (int j = 0; j < 8; ++j) w[j] = f2bf(lp[j * 128]);
      *reinterpret_cast<u16x8*>(&dst[o * 8]) = w;
    }
    __syncthreads();
    src = nsrc;
    dst = ndst;
    N = nN;
  }
}

// ---------------- plan: padded segments + tile->expert + loss ----------------
__global__ void plan_kernel(const int* __restrict__ cnt, const float* __restrict__ probsum,
                            int* __restrict__ meta, float* __restrict__ out) {
  if (threadIdx.x == 0) {
    int S = 0;
    for (int e = 0; e < NE; ++e) {
      meta[e] = S;
      const int pad = (cnt[e] + 127) & ~127;
      for (int t = S >> 7; t < (S + pad) >> 7; ++t) meta[16 + t] = e;
      S += pad;
    }
    meta[8] = S;
    for (int t = S >> 7; t < 24; ++t) meta[16 + t] = 0;
    float s = 0.0f;
    for (int e = 0; e < NE; ++e) s += (float)cnt[e] * probsum[e];
    out[(size_t)TT * HH] = s * (0.001f * (float)NE / ((float)TT * (float)TT));
  }
}

// ---------------- gather: x -> tiled bf16 Xc (+tokmap) ----------------
__global__ __launch_bounds__(256) void gather_kernel(
    const float* __restrict__ x, const float* __restrict__ score,
    const int* __restrict__ list, const int* __restrict__ cnt,
    const int* __restrict__ meta, u16* __restrict__ Xc, int* __restrict__ tokmap) {
  const int task = blockIdx.x * 4 + (threadIdx.x >> 6);
  const int lane = threadIdx.x & 63;
  const int pb = task / 24;  // 16-row block, 0..319
  const int c = task % 24;   // k chunk
  const int fq = lane >> 4, fr = lane & 15;
  const int p = pb * 16 + fr;
  int tok;
  float sc;
  if (p >= RSLOTS) {
    tok = p - RSLOTS;
    sc = 1.0f;
  } else {
    const int e = meta[16 + (p >> 7)];
    const int idx = p - meta[e];
    tok = (idx >= 0 && idx < cnt[e]) ? list[e * TT + idx] : -1;
    sc = (tok >= 0) ? score[tok] : 0.0f;
  }
  u16x8 w = {0, 0, 0, 0, 0, 0, 0, 0};
  if (tok >= 0) {
    const float* xp = x + (size_t)tok * HH + c * 32 + fq * 8;
    const f32x4 a = *reinterpret_cast<const f32x4*>(xp);
    const f32x4 b = *reinterpret_cast<const f32x4*>(xp + 4);
#pragma unroll
    for (int j = 0; j < 4; ++j) {
      w[j] = f2bf(a[j] * sc);
      w[j + 4] = f2bf(b[j] * sc);
    }
  }
  *reinterpret_cast<u16x8*>(&Xc[((size_t)(pb >> 3) * 24 + c) * 4096 + (pb & 7) * 512 +
                                lane * 8]) = w;
  if (c == 0 && fq == 0) tokmap[p] = tok;
}

// ---------------- stage A: P = silu(Xc Wg) * (Xc Wu) ----------------
// grid (16 nt, 40 mty): mty<24 routed (early-exit past Rp), >=24 shared (e=8).
__global__ __launch_bounds__(256, 2) void stageA_kernel(
    const u16* __restrict__ Xc, const int* __restrict__ meta,
    const u16* __restrict__ Wgt, const u16* __restrict__ Wut, u16* __restrict__ P) {
  const int mty = blockIdx.y, nt = blockIdx.x;
  int e;
  if (mty < 24) {
    if (mty * 128 >= meta[8]) return;
    e = meta[16 + mty];
  } else {
    e = 8;
  }
  const u16* wg = Wgt + (size_t)(e * 16 + nt) * 24 * 4096;
  const u16* wu = Wut + (size_t)(e * 16 + nt) * 24 * 4096;
  const u16* xa = Xc + (size_t)mty * 24 * 4096;

  __shared__ u16 As[2][4096], Bgs[2][4096], Bus[2][4096];

  const int tid = threadIdx.x, lane = tid & 63, wid = tid >> 6;
  const int fr = lane & 15, fq = lane >> 4;
  const int wm4 = (wid >> 1) * 4;  // row 16-block base
  const int wn4 = (wid & 1) * 4;   // col 16-block base
  const int wn = (wid & 1) * 64;
  const int ncol = nt * 128;
  const int so = wid * 1024 + lane * 8;  // gll global src offset (u16)
  const int sl = wid * 1024;             // gll LDS dst offset (u16), wave-uniform

  f32x4 accg[4][4], accu[4][4];
#pragma unroll
  for (int i = 0; i < 4; ++i)
#pragma unroll
    for (int j = 0; j < 4; ++j) {
      accg[i][j] = f32x4{0.f, 0.f, 0.f, 0.f};
      accu[i][j] = f32x4{0.f, 0.f, 0.f, 0.f};
    }

  // full chunk = 4096 u16; 4 waves x 2 gll16 x 512 u16 each
#define STAGE(c, buf)                                               \
  {                                                                 \
    gll16(xa + (size_t)(c) * 4096 + so, &As[buf][sl]);              \
    gll16(xa + (size_t)(c) * 4096 + so + 512, &As[buf][sl + 512]);  \
    gll16(wg + (size_t)(c) * 4096 + so, &Bgs[buf][sl]);             \
    gll16(wg + (size_t)(c) * 4096 + so + 512, &Bgs[buf][sl + 512]); \
    gll16(wu + (size_t)(c) * 4096 + so, &Bus[buf][sl]);             \
    gll16(wu + (size_t)(c) * 4096 + so + 512, &Bus[buf][sl + 512]); \
  }

  STAGE(0, 0)
  __syncthreads();
  int cur = 0;
  for (int c = 0; c < 24; ++c) {
    if (c < 23) STAGE(c + 1, cur ^ 1)
    s16x8 af[4], bg[4], bu[4];
#pragma unroll
    for (int i = 0; i < 4; ++i) {
      af[i] = *reinterpret_cast<const s16x8*>(&As[cur][(wm4 + i) * 512 + fq * 128 + fr * 8]);
      bg[i] = *reinterpret_cast<const s16x8*>(&Bgs[cur][(wn4 + i) * 512 + fq * 128 + fr * 8]);
      bu[i] = *reinterpret_cast<const s16x8*>(&Bus[cur][(wn4 + i) * 512 + fq * 128 + fr * 8]);
    }
#pragma unroll
    for (int j = 0; j < 4; ++j)
#pragma unroll
      for (int i = 0; i < 4; ++i) {
        accg[i][j] = __builtin_amdgcn_mfma_f32_16x16x32_bf16(af[i], bg[j], accg[i][j], 0, 0, 0);
        accu[i][j] = __builtin_amdgcn_mfma_f32_16x16x32_bf16(af[i], bu[j], accu[i][j], 0, 0, 0);
      }
    __syncthreads();
    cur ^= 1;
  }
#undef STAGE

  // epilogue: silu(g)*u -> P tiled bf16 (C/D: row=fq*4+reg, col=fr)
#pragma unroll
  for (int i = 0; i < 4; ++i)
#pragma unroll
    for (int cc = 0; cc < 4; ++cc) {
      const int rlo = fq * 4 + cc;  // row & 15 within 16-block (wm4+i)
#pragma unroll
      for (int j = 0; j < 4; ++j) {
        const int k = ncol + wn + j * 16 + fr;  // global i-col
        const float gv = accg[i][j][cc];
        const float val = (gv / (1.0f + __expf(-gv))) * accu[i][j][cc];
        P[((size_t)mty * 64 + (k >> 5)) * 4096 + (size_t)(wm4 + i) * 512 +
          ((k >> 3) & 3) * 128 + rlo * 8 + (k & 7)] = f2bf(val);
      }
    }
}

// ---------------- stage B: out += P Wd (atomicAdd, out pre-zeroed) ----------------
// grid (6 nt, 40 mty); each out element gets one shared + at most one routed add.
__global__ __launch_bounds__(256, 2) void stageB_kernel(
    const u16* __restrict__ P, const int* __restrict__ meta,
    const int* __restrict__ tokmap, const u16* __restrict__ Wdt,
    float* __restrict__ out) {
  const int mty = blockIdx.y, nt = blockIdx.x;
  int e;
  if (mty < 24) {
    if (mty * 128 >= meta[8]) return;
    e = meta[16 + mty];
  } else {
    e = 8;
  }
  const u16* wd = Wdt + (size_t)(e * 6 + nt) * 64 * 4096;
  const u16* pa = P + (size_t)mty * 64 * 4096;

  __shared__ u16 As[2][4096], Bs[2][4096];

  const int tid = threadIdx.x, lane = tid & 63, wid = tid >> 6;
  const int fr = lane & 15, fq = lane >> 4;
  const int wm4 = (wid >> 1) * 4;
  const int wn4 = (wid & 1) * 4;
  const int wm = (wid >> 1) * 64;
  const int wn = (wid & 1) * 64;
  const int ncol = nt * 128;
  const int so = wid * 1024 + lane * 8;
  const int sl = wid * 1024;

  f32x4 acc[4][4];
#pragma unroll
  for (int i = 0; i < 4; ++i)
#pragma unroll
    for (int j = 0; j < 4; ++j) acc[i][j] = f32x4{0.f, 0.f, 0.f, 0.f};

#define STAGEB(c, buf)                                              \
  {                                                                 \
    gll16(pa + (size_t)(c) * 4096 + so, &As[buf][sl]);              \
    gll16(pa + (size_t)(c) * 4096 + so + 512, &As[buf][sl + 512]);  \
    gll16(wd + (size_t)(c) * 4096 + so, &Bs[buf][sl]);              \
    gll16(wd + (size_t)(c) * 4096 + so + 512, &Bs[buf][sl + 512]);  \
  }

  STAGEB(0, 0)
  __syncthreads();
  int cur = 0;
  for (int c = 0; c < 64; ++c) {
    if (c < 63) STAGEB(c + 1, cur ^ 1)
    s16x8 af[4], bf[4];
#pragma unroll
    for (int i = 0; i < 4; ++i) {
      af[i] = *reinterpret_cast<const s16x8*>(&As[cur][(wm4 + i) * 512 + fq * 128 + fr * 8]);
      bf[i] = *reinterpret_cast<const s16x8*>(&Bs[cur][(wn4 + i) * 512 + fq * 128 + fr * 8]);
    }
#pragma unroll
    for (int j = 0; j < 4; ++j)
#pragma unroll
      for (int i = 0; i < 4; ++i)
        acc[i][j] = __builtin_amdgcn_mfma_f32_16x16x32_bf16(af[i], bf[j], acc[i][j], 0, 0, 0);
    __syncthreads();
    cur ^= 1;
  }
#undef STAGEB

#pragma unroll
  for (int i = 0; i < 4; ++i)
#pragma unroll
    for (int cc = 0; cc < 4; ++cc) {
      const int p = mty * 128 + wm + i * 16 + fq * 4 + cc;
      const int tok = tokmap[p];
      if (tok >= 0) {
#pragma unroll
        for (int j = 0; j < 4; ++j)
          atomicAdd(&out[(size_t)tok * HH + ncol + wn + j * 16 + fr], acc[i][j][cc]);
      }
    }
}

// ---------------- launcher ----------------
extern "C" void kernel_launch(void* const* d_in, const int* in_sizes, int n_in,
                              void* d_out, int out_size, void* d_ws, size_t ws_size,
                              hipStream_t stream) {
  (void)in_sizes; (void)n_in; (void)ws_size;
  const float* x = (const float*)d_in[0];
  const float* rw = (const float*)d_in[1];
  const float* gate_w = (const float*)d_in[2];
  const float* up_w = (const float*)d_in[3];
  const float* down_w = (const float*)d_in[4];
  const float* sh_gate = (const float*)d_in[5];
  const float* sh_up = (const float*)d_in[6];
  const float* sh_down = (const float*)d_in[7];
  float* out = (float*)d_out;

  char* ws = (char*)d_ws;
  size_t off = 0;
  u16* Xc = (u16*)(ws + off);  off += (size_t)(RSLOTS + TT) * HH * sizeof(u16);   // 7.9MB
  u16* P = (u16*)(ws + off);   off += (size_t)(RSLOTS + TT) * II * sizeof(u16);   // 21MB
  u16* Wgt = (u16*)(ws + off); off += (size_t)9 * 16 * 24 * 4096 * sizeof(u16);   // 28.3MB
  u16* Wut = (u16*)(ws + off); off += (size_t)9 * 16 * 24 * 4096 * sizeof(u16);   // 28.3MB
  u16* Wdt = (u16*)(ws + off); off += (size_t)9 * 6 * 64 * 4096 * sizeof(u16);    // 28.3MB
  float* score = (float*)(ws + off);   off += TT * sizeof(float);
  int* list = (int*)(ws + off);        off += (size_t)NE * TT * sizeof(int);
  int* cnt = (int*)(ws + off);         off += 16 * sizeof(int);
  float* probsum = (float*)(ws + off); off += 16 * sizeof(float);
  int* meta = (int*)(ws + off);        off += 64 * sizeof(int);
  int* tokmap = (int*)(ws + off);

  hipMemsetAsync(d_out, 0, (size_t)out_size * sizeof(float), stream);
  hipMemsetAsync(cnt, 0, 16 * sizeof(int) + 16 * sizeof(float), stream);
  wconv_router_kernel<<<dim3(WGRID + 512), dim3(256), 0, stream>>>(
      gate_w, up_w, down_w, sh_gate, sh_up, sh_down, Wgt, Wut, Wdt, x, rw, score,
      list, cnt, probsum);
  plan_kernel<<<dim3(1), dim3(64), 0, stream>>>(cnt, probsum, meta, out);
  gather_kernel<<<dim3(1920), dim3(256), 0, stream>>>(x, score, list, cnt, meta, Xc,
                                                      tokmap);
  stageA_kernel<<<dim3(16, 40, 1), dim3(256), 0, stream>>>(Xc, meta, Wgt, Wut, P);
  stageB_kernel<<<dim3(6, 40, 1), dim3(256), 0, stream>>>(P, meta, tokmap, Wdt, out);
}